// Round 1
// baseline (2376.279 us; speedup 1.0000x reference)
//
#include <hip/hip_runtime.h>
#include <math.h>

#define B 8
#define N 4096
#define S 1024
#define K 32
#define CIN 64
#define DIM 128
#define NH 4
#define HD 32
#define PTROW 68   // xyz(3) + points(64) + pad(1)

// ---------------- prep: fold BN + biases + Wp into one [71][128] matrix ----------------
// feat channels: 0..2 rel_xyz, 3..66 grouped_pts, 67..69 abs_xyz, row 70 = bias
__global__ void k_prep(const float* __restrict__ Wc, const float* __restrict__ bc,
                       const float* __restrict__ gamma, const float* __restrict__ beta,
                       const float* __restrict__ mean, const float* __restrict__ var,
                       const float* __restrict__ Wp, const float* __restrict__ bp,
                       float* __restrict__ Wall) {
    int d = threadIdx.x;
    if (d >= DIM) return;
    float a = gamma[d] / sqrtf(var[d] + 1e-5f);
    for (int c = 0; c < 67; c++) Wall[c * DIM + d] = Wc[d * 67 + c] * a;
    for (int c = 0; c < 3; c++)  Wall[(67 + c) * DIM + d] = Wp[c * DIM + d];
    Wall[70 * DIM + d] = bc[d] * a + beta[d] - mean[d] * a + bp[d];
}

// ---------------- transpose points (+xyz) into row-per-point layout ----------------
__global__ void k_transpose(const float* __restrict__ xyz, const float* __restrict__ points,
                            float* __restrict__ ptsT) {
    int idx = blockIdx.x * 256 + threadIdx.x;
    const int total = B * N * PTROW;
    if (idx >= total) return;
    int c = idx % PTROW;
    int n = (idx / PTROW) % N;
    int b = idx / (PTROW * N);
    float v = 0.0f;
    if (c < 3) v = xyz[(b * 3 + c) * N + n];
    else if (c < 67) v = points[(b * CIN + (c - 3)) * N + n];
    ptsT[idx] = v;
}

// ---------------- farthest point sampling ----------------
__global__ __launch_bounds__(1024) void k_fps(const float* __restrict__ xyz,
                                              int* __restrict__ fidx,
                                              float* __restrict__ nxyz,
                                              float* __restrict__ out_xyz) {
    const int b = blockIdx.x;
    const float* X = xyz + (size_t)b * 3 * N;
    __shared__ float xs[N], ys[N], zs[N];
    __shared__ float wval[16];
    __shared__ int widx[16];
    __shared__ int s_best;
    const int tid = threadIdx.x;

    float px[4], py[4], pz[4], pd[4];
#pragma unroll
    for (int i = 0; i < 4; i++) {
        int n = tid + i * 1024;
        px[i] = X[n]; py[i] = X[N + n]; pz[i] = X[2 * N + n];
        xs[n] = px[i]; ys[n] = py[i]; zs[n] = pz[i];
        pd[i] = 1e10f;
    }
    __syncthreads();

    int best = 0;
    for (int t = 0; t < S; t++) {
        float cx = xs[best], cy = ys[best], cz = zs[best];
        if (tid == 0) {
            fidx[b * S + t] = best;
            nxyz[(b * S + t) * 3 + 0] = cx;
            nxyz[(b * S + t) * 3 + 1] = cy;
            nxyz[(b * S + t) * 3 + 2] = cz;
            out_xyz[b * 3 * S + t] = cx;
            out_xyz[b * 3 * S + S + t] = cy;
            out_xyz[b * 3 * S + 2 * S + t] = cz;
        }
        if (t == S - 1) break;

        float bv = -1.0f; int bi = 0;
#pragma unroll
        for (int i = 0; i < 4; i++) {
            float dx = px[i] - cx, dy = py[i] - cy, dz = pz[i] - cz;
            // match XLA: (dx*dx + dy*dy) + dz*dz, no FMA contraction
            float d = __fadd_rn(__fadd_rn(__fmul_rn(dx, dx), __fmul_rn(dy, dy)), __fmul_rn(dz, dz));
            pd[i] = fminf(pd[i], d);
            if (pd[i] > bv) { bv = pd[i]; bi = tid + i * 1024; }
        }
        // wave argmax (first-index tie-break)
#pragma unroll
        for (int off = 1; off < 64; off <<= 1) {
            float ov = __shfl_xor(bv, off);
            int oi = __shfl_xor(bi, off);
            if (ov > bv || (ov == bv && oi < bi)) { bv = ov; bi = oi; }
        }
        int wid = tid >> 6;
        if ((tid & 63) == 0) { wval[wid] = bv; widx[wid] = bi; }
        __syncthreads();
        if (tid < 64) {
            float v = (tid < 16) ? wval[tid] : -1.0f;
            int ix = (tid < 16) ? widx[tid] : 0x7fffffff;
#pragma unroll
            for (int off = 1; off < 16; off <<= 1) {
                float ov = __shfl_xor(v, off);
                int oi = __shfl_xor(ix, off);
                if (ov > v || (ov == v && oi < ix)) { v = ov; ix = oi; }
            }
            if (tid == 0) s_best = ix;
        }
        __syncthreads();
        best = s_best;
    }
}

// ---------------- ball query: first 32 indices (ascending) with d <= r^2 ----------------
__global__ void k_ball(const float* __restrict__ xyz, const float* __restrict__ nxyz,
                       int* __restrict__ gidx) {
    const int g = blockIdx.x * 4 + (threadIdx.x >> 6);
    const int lane = threadIdx.x & 63;
    const int b = g >> 10;
    const float* X = xyz + (size_t)b * 3 * N;
    float cx = nxyz[g * 3 + 0], cy = nxyz[g * 3 + 1], cz = nxyz[g * 3 + 2];
    int cnt = 0;
    int first = -1;
    for (int base = 0; base < N && cnt < K; base += 64) {
        int n = base + lane;
        float dx = cx - X[n], dy = cy - X[N + n], dz = cz - X[2 * N + n];
        float d = __fadd_rn(__fadd_rn(__fmul_rn(dx, dx), __fmul_rn(dy, dy)), __fmul_rn(dz, dz));
        bool in = (d <= 0.04f);
        unsigned long long m = __ballot(in);
        int pre = __popcll(m & ((1ull << lane) - 1ull));
        if (in && cnt + pre < K) gidx[g * K + cnt + pre] = n;
        if (first < 0 && m) first = base + (int)__ffsll((unsigned long long)m) - 1;
        cnt += __popcll(m);
    }
    if (cnt < K) {
        for (int i = cnt + lane; i < K; i += 64) gidx[g * K + i] = first;
    }
}

// ---------------- fused group kernel: feat -> x -> attention -> residual -> maxpool ----------------
__global__ __launch_bounds__(256) void k_group(
    const float* __restrict__ ptsT, const float* __restrict__ nxyz,
    const int* __restrict__ gidx, const float* __restrict__ Wall,
    const float* __restrict__ Wq, const float* __restrict__ Wk,
    const float* __restrict__ Wv, const float* __restrict__ Wo,
    float* __restrict__ outp) {
    __shared__ float Abuf[K * DIM];   // feat -> q -> o
    __shared__ float Cbuf[K * DIM];   // (nidx/ctr) -> xs -> scores
    __shared__ float Kbuf[K * DIM];   // k -> maxpool redbuf
    __shared__ float Vbuf[K * DIM];   // v
    const int g = blockIdx.x, b = g >> 10, s = g & 1023;
    const int tid = threadIdx.x;

    int* nidx = (int*)Cbuf;
    float* ctr = Cbuf + 40;
    if (tid < K) nidx[tid] = gidx[g * K + tid];
    if (tid < 3) ctr[tid] = nxyz[g * 3 + tid];
    __syncthreads();

    // gather features into Abuf[p][c], c: 0..2 rel, 3..66 pts, 67..69 abs
    for (int i = tid; i < K * PTROW; i += 256) {
        int p = i / PTROW, c = i - p * PTROW;
        if (c == 67) continue;
        float v = ptsT[(size_t)(b * N + nidx[p]) * PTROW + c];
        if (c < 3) { Abuf[p * DIM + 67 + c] = v; Abuf[p * DIM + c] = v - ctr[c]; }
        else Abuf[p * DIM + c] = v;
    }
    __syncthreads();

    const int di = tid & 31, pi = tid >> 5;
    const int d0 = di * 4, p0 = pi * 4;

    // x = feat @ Wall + bias (keep residual copy in registers)
    float xr[4][4];
    {
        float4 bias = *(const float4*)&Wall[70 * DIM + d0];
#pragma unroll
        for (int i = 0; i < 4; i++) { xr[i][0] = bias.x; xr[i][1] = bias.y; xr[i][2] = bias.z; xr[i][3] = bias.w; }
        for (int c = 0; c < 70; c++) {
            float4 w = *(const float4*)&Wall[c * DIM + d0];
#pragma unroll
            for (int i = 0; i < 4; i++) {
                float f = Abuf[(p0 + i) * DIM + c];
                xr[i][0] += f * w.x; xr[i][1] += f * w.y; xr[i][2] += f * w.z; xr[i][3] += f * w.w;
            }
        }
    }
    __syncthreads();           // feat reads + nidx reads done
#pragma unroll
    for (int i = 0; i < 4; i++)
        *(float4*)&Cbuf[(p0 + i) * DIM + d0] = make_float4(xr[i][0], xr[i][1], xr[i][2], xr[i][3]);
    __syncthreads();           // xs ready, Abuf free

    // q,k,v = xs @ {Wq,Wk,Wv}
#pragma unroll
    for (int m = 0; m < 3; m++) {
        const float* W = (m == 0) ? Wq : (m == 1) ? Wk : Wv;
        float* dst = (m == 0) ? Abuf : (m == 1) ? Kbuf : Vbuf;
        float acc[4][4] = {};
        for (int c = 0; c < DIM; c++) {
            float4 w = *(const float4*)&W[c * DIM + d0];
#pragma unroll
            for (int i = 0; i < 4; i++) {
                float f = Cbuf[(p0 + i) * DIM + c];
                acc[i][0] += f * w.x; acc[i][1] += f * w.y; acc[i][2] += f * w.z; acc[i][3] += f * w.w;
            }
        }
#pragma unroll
        for (int i = 0; i < 4; i++)
            *(float4*)&dst[(p0 + i) * DIM + d0] = make_float4(acc[i][0], acc[i][1], acc[i][2], acc[i][3]);
    }
    __syncthreads();           // q,k,v ready; Cbuf(xs) free (residual in regs)

    // scores: wave h computes 32x32 for its head; 4x4 tiles per lane
    {
        const int h = tid >> 6, lane = tid & 63;
        const int ps = (lane >> 3) * 4, ks0 = (lane & 7) * 4;
        const int rot = (lane & 7) * 4;
        float sc[4][4] = {};
        for (int jj = 0; jj < HD; jj += 4) {
            int j = (jj + rot) & (HD - 1);
            float4 qv[4], kv[4];
#pragma unroll
            for (int i = 0; i < 4; i++) qv[i] = *(float4*)&Abuf[(ps + i) * DIM + h * HD + j];
#pragma unroll
            for (int l = 0; l < 4; l++) kv[l] = *(float4*)&Kbuf[(ks0 + l) * DIM + h * HD + j];
#pragma unroll
            for (int i = 0; i < 4; i++)
#pragma unroll
                for (int l = 0; l < 4; l++)
                    sc[i][l] += qv[i].x * kv[l].x + qv[i].y * kv[l].y + qv[i].z * kv[l].z + qv[i].w * kv[l].w;
        }
        const float scale = 0.17677669529663687f;  // 32^-0.5
#pragma unroll
        for (int i = 0; i < 4; i++)
            *(float4*)&Cbuf[(h * K + ps + i) * K + ks0] =
                make_float4(sc[i][0] * scale, sc[i][1] * scale, sc[i][2] * scale, sc[i][3] * scale);
    }
    __syncthreads();

    // softmax over k (rows = 4 heads x 32 queries)
    if (tid < NH * K) {
        float* row = &Cbuf[tid * K];
        float m = row[0];
#pragma unroll
        for (int j = 1; j < K; j++) m = fmaxf(m, row[j]);
        float sum = 0.0f;
#pragma unroll
        for (int j = 0; j < K; j++) { float e = __expf(row[j] - m); row[j] = e; sum += e; }
        float inv = 1.0f / sum;
#pragma unroll
        for (int j = 0; j < K; j++) row[j] *= inv;
    }
    __syncthreads();

    // o = probs @ v  -> Abuf (q dead)
    {
        const int hh = di >> 3;
        float oo[4][4] = {};
        for (int kk = 0; kk < K; kk++) {
            float4 vv = *(const float4*)&Vbuf[kk * DIM + d0];
#pragma unroll
            for (int i = 0; i < 4; i++) {
                float pw = Cbuf[(hh * K + p0 + i) * K + kk];
                oo[i][0] += pw * vv.x; oo[i][1] += pw * vv.y; oo[i][2] += pw * vv.z; oo[i][3] += pw * vv.w;
            }
        }
        __syncthreads();       // prob reads everywhere done before overwriting Abuf? (Abuf!=Cbuf, but keep order safe)
#pragma unroll
        for (int i = 0; i < 4; i++)
            *(float4*)&Abuf[(p0 + i) * DIM + d0] = make_float4(oo[i][0], oo[i][1], oo[i][2], oo[i][3]);
    }
    __syncthreads();

    // out = x + o @ Wo ; maxpool over K
    {
        float f4[4][4];
#pragma unroll
        for (int i = 0; i < 4; i++)
#pragma unroll
            for (int j = 0; j < 4; j++) f4[i][j] = xr[i][j];
        for (int c = 0; c < DIM; c++) {
            float4 w = *(const float4*)&Wo[c * DIM + d0];
#pragma unroll
            for (int i = 0; i < 4; i++) {
                float f = Abuf[(p0 + i) * DIM + c];
                f4[i][0] += f * w.x; f4[i][1] += f * w.y; f4[i][2] += f * w.z; f4[i][3] += f * w.w;
            }
        }
        float m0 = fmaxf(fmaxf(f4[0][0], f4[1][0]), fmaxf(f4[2][0], f4[3][0]));
        float m1 = fmaxf(fmaxf(f4[0][1], f4[1][1]), fmaxf(f4[2][1], f4[3][1]));
        float m2 = fmaxf(fmaxf(f4[0][2], f4[1][2]), fmaxf(f4[2][2], f4[3][2]));
        float m3 = fmaxf(fmaxf(f4[0][3], f4[1][3]), fmaxf(f4[2][3], f4[3][3]));
        *(float4*)&Kbuf[pi * DIM + d0] = make_float4(m0, m1, m2, m3);
    }
    __syncthreads();
    if (tid < DIM) {
        float m = Kbuf[tid];
#pragma unroll
        for (int q = 1; q < 8; q++) m = fmaxf(m, Kbuf[q * DIM + tid]);
        outp[(size_t)(b * DIM + tid) * S + s] = m;
    }
}

extern "C" void kernel_launch(void* const* d_in, const int* in_sizes, int n_in,
                              void* d_out, int out_size, void* d_ws, size_t ws_size,
                              hipStream_t stream) {
    const float* xyz = (const float*)d_in[0];
    const float* points = (const float*)d_in[1];
    const float* Wc = (const float*)d_in[2];
    const float* bc = (const float*)d_in[3];
    const float* gamma = (const float*)d_in[4];
    const float* beta = (const float*)d_in[5];
    const float* mean = (const float*)d_in[6];
    const float* var = (const float*)d_in[7];
    const float* Wq = (const float*)d_in[8];
    const float* Wk = (const float*)d_in[9];
    const float* Wv = (const float*)d_in[10];
    const float* Wo = (const float*)d_in[11];
    const float* Wp = (const float*)d_in[12];
    const float* bp = (const float*)d_in[13];

    float* out_xyz = (float*)d_out;
    float* out_pts = out_xyz + B * 3 * S;

    char* ws = (char*)d_ws;
    float* ptsT = (float*)ws;
    size_t off = (size_t)B * N * PTROW * 4;          // 8,912,896
    int* fidx = (int*)(ws + off); off += (size_t)B * S * 4;
    float* nxyz = (float*)(ws + off); off += (size_t)B * S * 3 * 4;
    int* gidxp = (int*)(ws + off); off += (size_t)B * S * K * 4;
    float* Wall = (float*)(ws + off); off += 71 * DIM * 4;

    k_prep<<<1, 128, 0, stream>>>(Wc, bc, gamma, beta, mean, var, Wp, bp, Wall);
    k_transpose<<<(B * N * PTROW + 255) / 256, 256, 0, stream>>>(xyz, points, ptsT);
    k_fps<<<B, 1024, 0, stream>>>(xyz, fidx, nxyz, out_xyz);
    k_ball<<<B * S / 4, 256, 0, stream>>>(xyz, nxyz, gidxp);
    k_group<<<B * S, 256, 0, stream>>>(ptsT, nxyz, gidxp, Wall, Wq, Wk, Wv, Wo, out_pts);
}

// Round 2
// 1577.422 us; speedup vs baseline: 1.5064x; 1.5064x over previous
//
#include <hip/hip_runtime.h>
#include <math.h>

#define B 8
#define N 4096
#define S 1024
#define K 32
#define CIN 64
#define DIM 128
#define NH 4
#define HD 32
#define PTROW 68   // xyz(3) + points(64) + pad(1)

// ---------------- prep: fold BN + biases + Wp into one [71][128] matrix ----------------
// feat channels: 0..2 rel_xyz, 3..66 grouped_pts, 67..69 abs_xyz, row 70 = bias
__global__ void k_prep(const float* __restrict__ Wc, const float* __restrict__ bc,
                       const float* __restrict__ gamma, const float* __restrict__ beta,
                       const float* __restrict__ mean, const float* __restrict__ var,
                       const float* __restrict__ Wp, const float* __restrict__ bp,
                       float* __restrict__ Wall) {
    int d = threadIdx.x;
    if (d >= DIM) return;
    float a = gamma[d] / sqrtf(var[d] + 1e-5f);
    for (int c = 0; c < 67; c++) Wall[c * DIM + d] = Wc[d * 67 + c] * a;
    for (int c = 0; c < 3; c++)  Wall[(67 + c) * DIM + d] = Wp[c * DIM + d];
    Wall[70 * DIM + d] = bc[d] * a + beta[d] - mean[d] * a + bp[d];
}

// ---------------- transpose points (+xyz) into row-per-point layout ----------------
__global__ void k_transpose(const float* __restrict__ xyz, const float* __restrict__ points,
                            float* __restrict__ ptsT) {
    int idx = blockIdx.x * 256 + threadIdx.x;
    const int total = B * N * PTROW;
    if (idx >= total) return;
    int c = idx % PTROW;
    int n = (idx / PTROW) % N;
    int b = idx / (PTROW * N);
    float v = 0.0f;
    if (c < 3) v = xyz[(b * 3 + c) * N + n];
    else if (c < 67) v = points[(b * CIN + (c - 3)) * N + n];
    ptsT[idx] = v;
}

// ---------------- farthest point sampling (latency-optimized) ----------------
// 256 threads, 16 pts/thread, packed-u64 argmax, ONE barrier per iteration.
__global__ __launch_bounds__(256) void k_fps(const float* __restrict__ xyz,
                                             float* __restrict__ nxyz,
                                             float* __restrict__ out_xyz) {
    const int b = blockIdx.x;
    const float* X = xyz + (size_t)b * 3 * N;
    __shared__ float xs[N], ys[N], zs[N];
    __shared__ unsigned long long wbuf[2][4];
    const int tid = threadIdx.x;
    const int PT = N / 256;  // 16

    float px[16], py[16], pz[16], pd[16];
#pragma unroll
    for (int i = 0; i < PT; i++) {
        int n = tid + i * 256;
        px[i] = X[n]; py[i] = X[N + n]; pz[i] = X[2 * N + n];
        xs[n] = px[i]; ys[n] = py[i]; zs[n] = pz[i];
        pd[i] = 1e10f;
    }
    __syncthreads();

    int best = 0;
    for (int t = 0; t < S; t++) {
        float cx = xs[best], cy = ys[best], cz = zs[best];
        if (tid == 0) {
            nxyz[(b * S + t) * 3 + 0] = cx;
            nxyz[(b * S + t) * 3 + 1] = cy;
            nxyz[(b * S + t) * 3 + 2] = cz;
            out_xyz[b * 3 * S + t] = cx;
            out_xyz[b * 3 * S + S + t] = cy;
            out_xyz[b * 3 * S + 2 * S + t] = cz;
        }
        if (t == S - 1) break;

        float bv = -1.0f; int bi = 0;
#pragma unroll
        for (int i = 0; i < PT; i++) {
            float dx = px[i] - cx, dy = py[i] - cy, dz = pz[i] - cz;
            // match XLA/np: (dx*dx + dy*dy) + dz*dz, no FMA contraction
            float d = __fadd_rn(__fadd_rn(__fmul_rn(dx, dx), __fmul_rn(dy, dy)), __fmul_rn(dz, dz));
            pd[i] = fminf(pd[i], d);
            if (pd[i] > bv) { bv = pd[i]; bi = tid + i * 256; }  // strict >: first idx within thread
        }
        // pack: max dist, then min index on ties (dist >= 0 so bits are order-preserving)
        unsigned long long key =
            ((unsigned long long)__float_as_uint(bv) << 32) | (unsigned)(0xFFFFFFFFu - (unsigned)bi);
#pragma unroll
        for (int off = 1; off < 64; off <<= 1) {
            unsigned long long o = __shfl_xor(key, off);
            if (o > key) key = o;
        }
        if ((tid & 63) == 0) wbuf[t & 1][tid >> 6] = key;
        __syncthreads();
        unsigned long long k0 = wbuf[t & 1][0], k1 = wbuf[t & 1][1];
        unsigned long long k2 = wbuf[t & 1][2], k3 = wbuf[t & 1][3];
        unsigned long long kA = k0 > k1 ? k0 : k1;
        unsigned long long kB = k2 > k3 ? k2 : k3;
        unsigned long long km = kA > kB ? kA : kB;
        best = (int)(0xFFFFFFFFu - (unsigned)km);
    }
}

// ---------------- ball query: first 32 indices (ascending) with d <= r^2 ----------------
__global__ void k_ball(const float* __restrict__ xyz, const float* __restrict__ nxyz,
                       int* __restrict__ gidx) {
    const int g = blockIdx.x * 4 + (threadIdx.x >> 6);
    const int lane = threadIdx.x & 63;
    const int b = g >> 10;
    const float* X = xyz + (size_t)b * 3 * N;
    float cx = nxyz[g * 3 + 0], cy = nxyz[g * 3 + 1], cz = nxyz[g * 3 + 2];
    int cnt = 0;
    int first = -1;
    for (int base = 0; base < N && cnt < K; base += 64) {
        int n = base + lane;
        float dx = cx - X[n], dy = cy - X[N + n], dz = cz - X[2 * N + n];
        float d = __fadd_rn(__fadd_rn(__fmul_rn(dx, dx), __fmul_rn(dy, dy)), __fmul_rn(dz, dz));
        bool in = (d <= 0.04f);
        unsigned long long m = __ballot(in);
        int pre = __popcll(m & ((1ull << lane) - 1ull));
        if (in && cnt + pre < K) gidx[g * K + cnt + pre] = n;
        if (first < 0 && m) first = base + (int)__ffsll((unsigned long long)m) - 1;
        cnt += __popcll(m);
    }
    if (cnt < K) {
        for (int i = cnt + lane; i < K; i += 64) gidx[g * K + i] = first;
    }
}

// ---------------- fused group kernel: feat -> x -> attention -> residual -> maxpool ----------------
__global__ __launch_bounds__(256) void k_group(
    const float* __restrict__ ptsT, const float* __restrict__ nxyz,
    const int* __restrict__ gidx, const float* __restrict__ Wall,
    const float* __restrict__ Wq, const float* __restrict__ Wk,
    const float* __restrict__ Wv, const float* __restrict__ Wo,
    float* __restrict__ outp) {
    __shared__ float Abuf[K * DIM];   // feat -> q -> o
    __shared__ float Cbuf[K * DIM];   // (nidx/ctr) -> xs -> scores
    __shared__ float Kbuf[K * DIM];   // k -> maxpool redbuf
    __shared__ float Vbuf[K * DIM];   // v
    const int g = blockIdx.x, b = g >> 10, s = g & 1023;
    const int tid = threadIdx.x;

    int* nidx = (int*)Cbuf;
    float* ctr = Cbuf + 40;
    if (tid < K) nidx[tid] = gidx[g * K + tid];
    if (tid < 3) ctr[tid] = nxyz[g * 3 + tid];
    __syncthreads();

    // gather features into Abuf[p][c], c: 0..2 rel, 3..66 pts, 67..69 abs
    for (int i = tid; i < K * PTROW; i += 256) {
        int p = i / PTROW, c = i - p * PTROW;
        if (c == 67) continue;
        float v = ptsT[(size_t)(b * N + nidx[p]) * PTROW + c];
        if (c < 3) { Abuf[p * DIM + 67 + c] = v; Abuf[p * DIM + c] = v - ctr[c]; }
        else Abuf[p * DIM + c] = v;
    }
    __syncthreads();

    const int di = tid & 31, pi = tid >> 5;
    const int d0 = di * 4, p0 = pi * 4;

    // x = feat @ Wall + bias (keep residual copy in registers)
    float xr[4][4];
    {
        float4 bias = *(const float4*)&Wall[70 * DIM + d0];
#pragma unroll
        for (int i = 0; i < 4; i++) { xr[i][0] = bias.x; xr[i][1] = bias.y; xr[i][2] = bias.z; xr[i][3] = bias.w; }
        for (int c = 0; c < 70; c++) {
            float4 w = *(const float4*)&Wall[c * DIM + d0];
#pragma unroll
            for (int i = 0; i < 4; i++) {
                float f = Abuf[(p0 + i) * DIM + c];
                xr[i][0] += f * w.x; xr[i][1] += f * w.y; xr[i][2] += f * w.z; xr[i][3] += f * w.w;
            }
        }
    }
    __syncthreads();           // feat reads + nidx reads done
#pragma unroll
    for (int i = 0; i < 4; i++)
        *(float4*)&Cbuf[(p0 + i) * DIM + d0] = make_float4(xr[i][0], xr[i][1], xr[i][2], xr[i][3]);
    __syncthreads();           // xs ready, Abuf free

    // q,k,v = xs @ {Wq,Wk,Wv}
#pragma unroll
    for (int m = 0; m < 3; m++) {
        const float* W = (m == 0) ? Wq : (m == 1) ? Wk : Wv;
        float* dst = (m == 0) ? Abuf : (m == 1) ? Kbuf : Vbuf;
        float acc[4][4] = {};
        for (int c = 0; c < DIM; c++) {
            float4 w = *(const float4*)&W[c * DIM + d0];
#pragma unroll
            for (int i = 0; i < 4; i++) {
                float f = Cbuf[(p0 + i) * DIM + c];
                acc[i][0] += f * w.x; acc[i][1] += f * w.y; acc[i][2] += f * w.z; acc[i][3] += f * w.w;
            }
        }
#pragma unroll
        for (int i = 0; i < 4; i++)
            *(float4*)&dst[(p0 + i) * DIM + d0] = make_float4(acc[i][0], acc[i][1], acc[i][2], acc[i][3]);
    }
    __syncthreads();           // q,k,v ready; Cbuf(xs) free (residual in regs)

    // scores: wave h computes 32x32 for its head; 4x4 tiles per lane
    {
        const int h = tid >> 6, lane = tid & 63;
        const int ps = (lane >> 3) * 4, ks0 = (lane & 7) * 4;
        const int rot = (lane & 7) * 4;
        float sc[4][4] = {};
        for (int jj = 0; jj < HD; jj += 4) {
            int j = (jj + rot) & (HD - 1);
            float4 qv[4], kv[4];
#pragma unroll
            for (int i = 0; i < 4; i++) qv[i] = *(float4*)&Abuf[(ps + i) * DIM + h * HD + j];
#pragma unroll
            for (int l = 0; l < 4; l++) kv[l] = *(float4*)&Kbuf[(ks0 + l) * DIM + h * HD + j];
#pragma unroll
            for (int i = 0; i < 4; i++)
#pragma unroll
                for (int l = 0; l < 4; l++)
                    sc[i][l] += qv[i].x * kv[l].x + qv[i].y * kv[l].y + qv[i].z * kv[l].z + qv[i].w * kv[l].w;
        }
        const float scale = 0.17677669529663687f;  // 32^-0.5
#pragma unroll
        for (int i = 0; i < 4; i++)
            *(float4*)&Cbuf[(h * K + ps + i) * K + ks0] =
                make_float4(sc[i][0] * scale, sc[i][1] * scale, sc[i][2] * scale, sc[i][3] * scale);
    }
    __syncthreads();

    // softmax over k (rows = 4 heads x 32 queries)
    if (tid < NH * K) {
        float* row = &Cbuf[tid * K];
        float m = row[0];
#pragma unroll
        for (int j = 1; j < K; j++) m = fmaxf(m, row[j]);
        float sum = 0.0f;
#pragma unroll
        for (int j = 0; j < K; j++) { float e = __expf(row[j] - m); row[j] = e; sum += e; }
        float inv = 1.0f / sum;
#pragma unroll
        for (int j = 0; j < K; j++) row[j] *= inv;
    }
    __syncthreads();

    // o = probs @ v  -> Abuf (q dead)
    {
        const int hh = di >> 3;
        float oo[4][4] = {};
        for (int kk = 0; kk < K; kk++) {
            float4 vv = *(const float4*)&Vbuf[kk * DIM + d0];
#pragma unroll
            for (int i = 0; i < 4; i++) {
                float pw = Cbuf[(hh * K + p0 + i) * K + kk];
                oo[i][0] += pw * vv.x; oo[i][1] += pw * vv.y; oo[i][2] += pw * vv.z; oo[i][3] += pw * vv.w;
            }
        }
        __syncthreads();
#pragma unroll
        for (int i = 0; i < 4; i++)
            *(float4*)&Abuf[(p0 + i) * DIM + d0] = make_float4(oo[i][0], oo[i][1], oo[i][2], oo[i][3]);
    }
    __syncthreads();

    // out = x + o @ Wo ; maxpool over K
    {
        float f4[4][4];
#pragma unroll
        for (int i = 0; i < 4; i++)
#pragma unroll
            for (int j = 0; j < 4; j++) f4[i][j] = xr[i][j];
        for (int c = 0; c < DIM; c++) {
            float4 w = *(const float4*)&Wo[c * DIM + d0];
#pragma unroll
            for (int i = 0; i < 4; i++) {
                float f = Abuf[(p0 + i) * DIM + c];
                f4[i][0] += f * w.x; f4[i][1] += f * w.y; f4[i][2] += f * w.z; f4[i][3] += f * w.w;
            }
        }
        float m0 = fmaxf(fmaxf(f4[0][0], f4[1][0]), fmaxf(f4[2][0], f4[3][0]));
        float m1 = fmaxf(fmaxf(f4[0][1], f4[1][1]), fmaxf(f4[2][1], f4[3][1]));
        float m2 = fmaxf(fmaxf(f4[0][2], f4[1][2]), fmaxf(f4[2][2], f4[3][2]));
        float m3 = fmaxf(fmaxf(f4[0][3], f4[1][3]), fmaxf(f4[2][3], f4[3][3]));
        *(float4*)&Kbuf[pi * DIM + d0] = make_float4(m0, m1, m2, m3);
    }
    __syncthreads();
    if (tid < DIM) {
        float m = Kbuf[tid];
#pragma unroll
        for (int q = 1; q < 8; q++) m = fmaxf(m, Kbuf[q * DIM + tid]);
        outp[(size_t)(b * DIM + tid) * S + s] = m;
    }
}

extern "C" void kernel_launch(void* const* d_in, const int* in_sizes, int n_in,
                              void* d_out, int out_size, void* d_ws, size_t ws_size,
                              hipStream_t stream) {
    const float* xyz = (const float*)d_in[0];
    const float* points = (const float*)d_in[1];
    const float* Wc = (const float*)d_in[2];
    const float* bc = (const float*)d_in[3];
    const float* gamma = (const float*)d_in[4];
    const float* beta = (const float*)d_in[5];
    const float* mean = (const float*)d_in[6];
    const float* var = (const float*)d_in[7];
    const float* Wq = (const float*)d_in[8];
    const float* Wk = (const float*)d_in[9];
    const float* Wv = (const float*)d_in[10];
    const float* Wo = (const float*)d_in[11];
    const float* Wp = (const float*)d_in[12];
    const float* bp = (const float*)d_in[13];

    float* out_xyz = (float*)d_out;
    float* out_pts = out_xyz + B * 3 * S;

    char* ws = (char*)d_ws;
    float* ptsT = (float*)ws;
    size_t off = (size_t)B * N * PTROW * 4;          // 8,912,896
    float* nxyz = (float*)(ws + off); off += (size_t)B * S * 3 * 4;
    int* gidxp = (int*)(ws + off); off += (size_t)B * S * K * 4;
    float* Wall = (float*)(ws + off); off += 71 * DIM * 4;

    k_prep<<<1, 128, 0, stream>>>(Wc, bc, gamma, beta, mean, var, Wp, bp, Wall);
    k_transpose<<<(B * N * PTROW + 255) / 256, 256, 0, stream>>>(xyz, points, ptsT);
    k_fps<<<B, 256, 0, stream>>>(xyz, nxyz, out_xyz);
    k_ball<<<B * S / 4, 256, 0, stream>>>(xyz, nxyz, gidxp);
    k_group<<<B * S, 256, 0, stream>>>(ptsT, nxyz, gidxp, Wall, Wq, Wk, Wv, Wo, out_pts);
}

// Round 3
// 918.138 us; speedup vs baseline: 2.5882x; 1.7181x over previous
//
#include <hip/hip_runtime.h>
#include <math.h>

#define B 8
#define N 4096
#define S 1024
#define K 32
#define CIN 64
#define DIM 128
#define NH 4
#define HD 32
#define PTROW 68   // xyz(3) + points(64) + pad(1)

typedef __attribute__((ext_vector_type(8))) short bfrag;
typedef __attribute__((ext_vector_type(4))) float f32x4;

#define MFMA(a, b, c) __builtin_amdgcn_mfma_f32_16x16x32_bf16((a), (b), (c), 0, 0, 0)

__device__ __forceinline__ unsigned short f2bf(float f) {
    union { float f; unsigned u; } v; v.f = f;
    unsigned r = v.u + 0x7FFFu + ((v.u >> 16) & 1u);
    return (unsigned short)(r >> 16);
}

// ---------------- prep: fold BN + biases + Wp into one [71][128] matrix ----------------
__global__ void k_prep(const float* __restrict__ Wc, const float* __restrict__ bc,
                       const float* __restrict__ gamma, const float* __restrict__ beta,
                       const float* __restrict__ mean, const float* __restrict__ var,
                       const float* __restrict__ Wp, const float* __restrict__ bp,
                       float* __restrict__ Wall) {
    int d = threadIdx.x;
    if (d >= DIM) return;
    float a = gamma[d] / sqrtf(var[d] + 1e-5f);
    for (int c = 0; c < 67; c++) Wall[c * DIM + d] = Wc[d * 67 + c] * a;
    for (int c = 0; c < 3; c++)  Wall[(67 + c) * DIM + d] = Wp[c * DIM + d];
    Wall[70 * DIM + d] = bc[d] * a + beta[d] - mean[d] * a + bp[d];
}

// ---------------- prep2: swizzle weights into MFMA B-fragment order, bf16 ----------------
// frag layout per matrix: [kt][gnt(8)][lane(64)][8], elem = W[kt*32+(lane>>4)*8+i][gnt*16+(lane&15)]
// Wall: 3 kt (k>=70 zero-padded). Wq/Wk/Wv/Wo: 4 kt.
__global__ void k_prep2(const float* __restrict__ Wall, const float* __restrict__ Wq,
                        const float* __restrict__ Wk, const float* __restrict__ Wv,
                        const float* __restrict__ Wo, unsigned short* __restrict__ WF) {
    int blk = blockIdx.x;  // 0..18
    int mat, kt, base;
    if (blk < 3) { mat = 0; kt = blk; base = 0; }
    else { mat = 1 + (blk - 3) / 4; kt = (blk - 3) % 4; base = 12288 + (mat - 1) * 16384; }
    const float* W = (mat == 0) ? Wall : (mat == 1) ? Wq : (mat == 2) ? Wk : (mat == 3) ? Wv : Wo;
    int tid = threadIdx.x;  // 512
    int gnt = tid >> 6, lane = tid & 63;
    int n = gnt * 16 + (lane & 15);
    int k0 = kt * 32 + (lane >> 4) * 8;
    unsigned short* dst = WF + base + (size_t)((kt * 8 + gnt) * 64 + lane) * 8;
#pragma unroll
    for (int i = 0; i < 8; i++) {
        int k = k0 + i;
        float v = (mat == 0 && k >= 70) ? 0.0f : W[k * 128 + n];
        dst[i] = f2bf(v);
    }
}

// ---------------- transpose points (+xyz) into row-per-point layout ----------------
__global__ void k_transpose(const float* __restrict__ xyz, const float* __restrict__ points,
                            float* __restrict__ ptsT) {
    int idx = blockIdx.x * 256 + threadIdx.x;
    const int total = B * N * PTROW;
    if (idx >= total) return;
    int c = idx % PTROW;
    int n = (idx / PTROW) % N;
    int b = idx / (PTROW * N);
    float v = 0.0f;
    if (c < 3) v = xyz[(b * 3 + c) * N + n];
    else if (c < 67) v = points[(b * CIN + (c - 3)) * N + n];
    ptsT[idx] = v;
}

// ---------------- farthest point sampling (latency-optimized) ----------------
__global__ __launch_bounds__(256) void k_fps(const float* __restrict__ xyz,
                                             float* __restrict__ nxyz,
                                             float* __restrict__ out_xyz) {
    const int b = blockIdx.x;
    const float* X = xyz + (size_t)b * 3 * N;
    __shared__ float xs[N], ys[N], zs[N];
    __shared__ unsigned long long wbuf[2][4];
    const int tid = threadIdx.x;
    const int PT = N / 256;  // 16

    float px[16], py[16], pz[16], pd[16];
#pragma unroll
    for (int i = 0; i < PT; i++) {
        int n = tid + i * 256;
        px[i] = X[n]; py[i] = X[N + n]; pz[i] = X[2 * N + n];
        xs[n] = px[i]; ys[n] = py[i]; zs[n] = pz[i];
        pd[i] = 1e10f;
    }
    __syncthreads();

    int best = 0;
    for (int t = 0; t < S; t++) {
        float cx = xs[best], cy = ys[best], cz = zs[best];
        if (tid == 0) {
            nxyz[(b * S + t) * 3 + 0] = cx;
            nxyz[(b * S + t) * 3 + 1] = cy;
            nxyz[(b * S + t) * 3 + 2] = cz;
            out_xyz[b * 3 * S + t] = cx;
            out_xyz[b * 3 * S + S + t] = cy;
            out_xyz[b * 3 * S + 2 * S + t] = cz;
        }
        if (t == S - 1) break;

        float bv = -1.0f; int bi = 0;
#pragma unroll
        for (int i = 0; i < PT; i++) {
            float dx = px[i] - cx, dy = py[i] - cy, dz = pz[i] - cz;
            float d = __fadd_rn(__fadd_rn(__fmul_rn(dx, dx), __fmul_rn(dy, dy)), __fmul_rn(dz, dz));
            pd[i] = fminf(pd[i], d);
            if (pd[i] > bv) { bv = pd[i]; bi = tid + i * 256; }
        }
        unsigned long long key =
            ((unsigned long long)__float_as_uint(bv) << 32) | (unsigned)(0xFFFFFFFFu - (unsigned)bi);
#pragma unroll
        for (int off = 1; off < 64; off <<= 1) {
            unsigned long long o = __shfl_xor(key, off);
            if (o > key) key = o;
        }
        if ((tid & 63) == 0) wbuf[t & 1][tid >> 6] = key;
        __syncthreads();
        unsigned long long k0 = wbuf[t & 1][0], k1 = wbuf[t & 1][1];
        unsigned long long k2 = wbuf[t & 1][2], k3 = wbuf[t & 1][3];
        unsigned long long kA = k0 > k1 ? k0 : k1;
        unsigned long long kB = k2 > k3 ? k2 : k3;
        unsigned long long km = kA > kB ? kA : kB;
        best = (int)(0xFFFFFFFFu - (unsigned)km);
    }
}

// ---------------- ball query ----------------
__global__ void k_ball(const float* __restrict__ xyz, const float* __restrict__ nxyz,
                       int* __restrict__ gidx) {
    const int g = blockIdx.x * 4 + (threadIdx.x >> 6);
    const int lane = threadIdx.x & 63;
    const int b = g >> 10;
    const float* X = xyz + (size_t)b * 3 * N;
    float cx = nxyz[g * 3 + 0], cy = nxyz[g * 3 + 1], cz = nxyz[g * 3 + 2];
    int cnt = 0;
    int first = -1;
    for (int base = 0; base < N && cnt < K; base += 64) {
        int n = base + lane;
        float dx = cx - X[n], dy = cy - X[N + n], dz = cz - X[2 * N + n];
        float d = __fadd_rn(__fadd_rn(__fmul_rn(dx, dx), __fmul_rn(dy, dy)), __fmul_rn(dz, dz));
        bool in = (d <= 0.04f);
        unsigned long long m = __ballot(in);
        int pre = __popcll(m & ((1ull << lane) - 1ull));
        if (in && cnt + pre < K) gidx[g * K + cnt + pre] = n;
        if (first < 0 && m) first = base + (int)__ffsll((unsigned long long)m) - 1;
        cnt += __popcll(m);
    }
    if (cnt < K) {
        for (int i = cnt + lane; i < K; i += 64) gidx[g * K + i] = first;
    }
}

// ---------------- fused group kernel, MFMA version ----------------
// LDS regions (bytes):
#define LDS_X   0        // [32][128] bf16 swizzled: x -> P
#define LDS_A   8192     // [32][128] bf16 swizzled: feat -> q -> o
#define LDS_K   16384    // [32][128] bf16 swizzled: k
#define LDS_VT  24576    // v_t [128][56] bf16 (112B rows): v transposed
#define LDS_MISC 38912   // nidx[32] int, ctr[3] float
#define LDS_TOTAL 39056

#define LDSA_READ(off, row, colb) \
    (*(const bfrag*)(smem + (off) + ((row) << 8) + ((colb) ^ (((row) & 7) << 4))))
#define LDS_ST16(off, row, colb, val) \
    (*(unsigned short*)(smem + (off) + ((row) << 8) + ((colb) ^ (((row) & 7) << 4))) = (val))

__global__ __launch_bounds__(256, 4) void k_group(
    const float* __restrict__ ptsT, const float* __restrict__ nxyz,
    const int* __restrict__ gidx, const unsigned short* __restrict__ WF,
    const float* __restrict__ bias, float* __restrict__ outp) {
    __shared__ __align__(16) char smem[LDS_TOTAL];
    const int g = blockIdx.x, b = g >> 10, s = g & 1023;
    const int tid = threadIdx.x;
    const int w = tid >> 6, l = tid & 63;
    const int lane16 = l & 15, lquad = l >> 4;
    const int ncol = w * 32;

    int* nidx = (int*)(smem + LDS_MISC);
    float* ctr = (float*)(smem + LDS_MISC + 128);

    if (tid < K) nidx[tid] = gidx[g * K + tid];
    if (tid >= 64 && tid < 67) ctr[tid - 64] = nxyz[g * 3 + (tid - 64)];
    // zero feat cols 64..95 (K-padding for GEMM1)
    for (int i = tid; i < 32 * 32; i += 256) {
        int p = i >> 5, c = 64 + (i & 31);
        LDS_ST16(LDS_A, p, c * 2, (unsigned short)0);
    }
    __syncthreads();

    // gather feat -> LDS_A: cols 0..2 rel, 3..66 pts, 67..69 abs
    {
        const int p = tid >> 3, j = tid & 7;
        const float* src = ptsT + (size_t)(b * N + nidx[p]) * PTROW;
        float c0 = ctr[0], c1 = ctr[1], c2 = ctr[2];
        for (int c = j; c < 70; c += 8) {
            float v;
            if (c < 3) v = src[c] - (c == 0 ? c0 : c == 1 ? c1 : c2);
            else if (c < 67) v = src[c];
            else v = src[c - 67];
            LDS_ST16(LDS_A, p, c * 2, f2bf(v));
        }
    }
    __syncthreads();

    // ---- GEMM1: x = feat @ Wall + bias(+bp) ; residual kept in accx ----
    f32x4 accx[2][2];
    {
        float bv0 = bias[ncol + lane16], bv1 = bias[ncol + 16 + lane16];
        accx[0][0] = f32x4{bv0, bv0, bv0, bv0}; accx[1][0] = accx[0][0];
        accx[0][1] = f32x4{bv1, bv1, bv1, bv1}; accx[1][1] = accx[0][1];
        const bfrag* WallF = (const bfrag*)WF;
#pragma unroll
        for (int kt = 0; kt < 3; kt++) {
            bfrag a0 = LDSA_READ(LDS_A, lane16, kt * 64 + lquad * 16);
            bfrag a1 = LDSA_READ(LDS_A, 16 + lane16, kt * 64 + lquad * 16);
            bfrag b0 = WallF[(kt * 8 + w * 2 + 0) * 64 + l];
            bfrag b1 = WallF[(kt * 8 + w * 2 + 1) * 64 + l];
            accx[0][0] = MFMA(a0, b0, accx[0][0]);
            accx[0][1] = MFMA(a0, b1, accx[0][1]);
            accx[1][0] = MFMA(a1, b0, accx[1][0]);
            accx[1][1] = MFMA(a1, b1, accx[1][1]);
        }
        // write x (bf16) to LDS_X
#pragma unroll
        for (int mt = 0; mt < 2; mt++)
#pragma unroll
            for (int nt = 0; nt < 2; nt++)
#pragma unroll
                for (int r = 0; r < 4; r++)
                    LDS_ST16(LDS_X, mt * 16 + lquad * 4 + r, (ncol + nt * 16 + lane16) * 2,
                             f2bf(accx[mt][nt][r]));
    }
    __syncthreads();

    // ---- GEMM2-4: q,k,v = x @ {Wq,Wk,Wv} ----
    {
        const bfrag* WQF = (const bfrag*)(WF + 12288);
        const bfrag* WKF = (const bfrag*)(WF + 28672);
        const bfrag* WVF = (const bfrag*)(WF + 45056);
#pragma unroll
        for (int m = 0; m < 3; m++) {
            const bfrag* BW = (m == 0) ? WQF : (m == 1) ? WKF : WVF;
            f32x4 acc[2][2] = {};
#pragma unroll
            for (int kt = 0; kt < 4; kt++) {
                bfrag a0 = LDSA_READ(LDS_X, lane16, kt * 64 + lquad * 16);
                bfrag a1 = LDSA_READ(LDS_X, 16 + lane16, kt * 64 + lquad * 16);
                bfrag b0 = BW[(kt * 8 + w * 2 + 0) * 64 + l];
                bfrag b1 = BW[(kt * 8 + w * 2 + 1) * 64 + l];
                acc[0][0] = MFMA(a0, b0, acc[0][0]);
                acc[0][1] = MFMA(a0, b1, acc[0][1]);
                acc[1][0] = MFMA(a1, b0, acc[1][0]);
                acc[1][1] = MFMA(a1, b1, acc[1][1]);
            }
            if (m < 2) {
                int dst = (m == 0) ? LDS_A : LDS_K;
#pragma unroll
                for (int mt = 0; mt < 2; mt++)
#pragma unroll
                    for (int nt = 0; nt < 2; nt++)
#pragma unroll
                        for (int r = 0; r < 4; r++)
                            LDS_ST16(dst, mt * 16 + lquad * 4 + r, (ncol + nt * 16 + lane16) * 2,
                                     f2bf(acc[mt][nt][r]));
            } else {
                // v transposed: v_t[d][j], row stride 112B
#pragma unroll
                for (int mt = 0; mt < 2; mt++)
#pragma unroll
                    for (int nt = 0; nt < 2; nt++)
#pragma unroll
                        for (int r = 0; r < 4; r++) {
                            int d = ncol + nt * 16 + lane16;
                            int j = mt * 16 + lquad * 4 + r;
                            *(unsigned short*)(smem + LDS_VT + d * 112 + j * 2) = f2bf(acc[mt][nt][r]);
                        }
            }
        }
    }
    __syncthreads();

    // ---- scores (head h = w), in-register softmax, P -> LDS_X, PV, o -> LDS_A ----
    {
        const int h = w;
        const int hb = h * 64;  // byte offset of this head's 32 cols
        bfrag aq0 = LDSA_READ(LDS_A, lane16, hb + lquad * 16);
        bfrag aq1 = LDSA_READ(LDS_A, 16 + lane16, hb + lquad * 16);
        bfrag bk0 = LDSA_READ(LDS_K, lane16, hb + lquad * 16);
        bfrag bk1 = LDSA_READ(LDS_K, 16 + lane16, hb + lquad * 16);
        f32x4 sc[2][2] = {};
        sc[0][0] = MFMA(aq0, bk0, sc[0][0]);
        sc[0][1] = MFMA(aq0, bk1, sc[0][1]);
        sc[1][0] = MFMA(aq1, bk0, sc[1][0]);
        sc[1][1] = MFMA(aq1, bk1, sc[1][1]);

        const float scale = 0.17677669529663687f;
        float p_[2][2][4];
        float mx[2][4], sm[2][4];
#pragma unroll
        for (int mt = 0; mt < 2; mt++)
#pragma unroll
            for (int r = 0; r < 4; r++) {
                p_[mt][0][r] = sc[mt][0][r] * scale;
                p_[mt][1][r] = sc[mt][1][r] * scale;
                mx[mt][r] = fmaxf(p_[mt][0][r], p_[mt][1][r]);
            }
#pragma unroll
        for (int d = 1; d < 16; d <<= 1)
#pragma unroll
            for (int mt = 0; mt < 2; mt++)
#pragma unroll
                for (int r = 0; r < 4; r++)
                    mx[mt][r] = fmaxf(mx[mt][r], __shfl_xor(mx[mt][r], d));
#pragma unroll
        for (int mt = 0; mt < 2; mt++)
#pragma unroll
            for (int r = 0; r < 4; r++) {
                float e0 = __expf(p_[mt][0][r] - mx[mt][r]);
                float e1 = __expf(p_[mt][1][r] - mx[mt][r]);
                p_[mt][0][r] = e0; p_[mt][1][r] = e1;
                sm[mt][r] = e0 + e1;
            }
#pragma unroll
        for (int d = 1; d < 16; d <<= 1)
#pragma unroll
            for (int mt = 0; mt < 2; mt++)
#pragma unroll
                for (int r = 0; r < 4; r++)
                    sm[mt][r] += __shfl_xor(sm[mt][r], d);
#pragma unroll
        for (int mt = 0; mt < 2; mt++)
#pragma unroll
            for (int r = 0; r < 4; r++) {
                float inv = 1.0f / sm[mt][r];
                int row = mt * 16 + lquad * 4 + r;
                LDS_ST16(LDS_X, row, (h * 32 + lane16) * 2, f2bf(p_[mt][0][r] * inv));
                LDS_ST16(LDS_X, row, (h * 32 + 16 + lane16) * 2, f2bf(p_[mt][1][r] * inv));
            }

        // PV (same wave produced P rows & v_t rows for this head; no barrier needed)
        f32x4 oacc[2][2] = {};
        bfrag ap0 = LDSA_READ(LDS_X, lane16, hb + lquad * 16);
        bfrag ap1 = LDSA_READ(LDS_X, 16 + lane16, hb + lquad * 16);
        bfrag bv0 = *(const bfrag*)(smem + LDS_VT + (h * 32 + lane16) * 112 + lquad * 16);
        bfrag bv1 = *(const bfrag*)(smem + LDS_VT + (h * 32 + 16 + lane16) * 112 + lquad * 16);
        oacc[0][0] = MFMA(ap0, bv0, oacc[0][0]);
        oacc[0][1] = MFMA(ap0, bv1, oacc[0][1]);
        oacc[1][0] = MFMA(ap1, bv0, oacc[1][0]);
        oacc[1][1] = MFMA(ap1, bv1, oacc[1][1]);
        // o -> LDS_A (own head's cols; q there is dead for this wave)
#pragma unroll
        for (int mt = 0; mt < 2; mt++)
#pragma unroll
            for (int nt = 0; nt < 2; nt++)
#pragma unroll
                for (int r = 0; r < 4; r++)
                    LDS_ST16(LDS_A, mt * 16 + lquad * 4 + r, (h * 32 + nt * 16 + lane16) * 2,
                             f2bf(oacc[mt][nt][r]));
    }
    __syncthreads();

    // ---- GEMM7: out = x + o @ Wo ; maxpool over 32 points ----
    {
        const bfrag* WOF = (const bfrag*)(WF + 61440);
        f32x4 acc[2][2];
#pragma unroll
        for (int mt = 0; mt < 2; mt++)
#pragma unroll
            for (int nt = 0; nt < 2; nt++) acc[mt][nt] = accx[mt][nt];
#pragma unroll
        for (int kt = 0; kt < 4; kt++) {
            bfrag a0 = LDSA_READ(LDS_A, lane16, kt * 64 + lquad * 16);
            bfrag a1 = LDSA_READ(LDS_A, 16 + lane16, kt * 64 + lquad * 16);
            bfrag b0 = WOF[(kt * 8 + w * 2 + 0) * 64 + l];
            bfrag b1 = WOF[(kt * 8 + w * 2 + 1) * 64 + l];
            acc[0][0] = MFMA(a0, b0, acc[0][0]);
            acc[0][1] = MFMA(a0, b1, acc[0][1]);
            acc[1][0] = MFMA(a1, b0, acc[1][0]);
            acc[1][1] = MFMA(a1, b1, acc[1][1]);
        }
        float mnt[2];
#pragma unroll
        for (int nt = 0; nt < 2; nt++) {
            float m = acc[0][nt][0];
#pragma unroll
            for (int r = 1; r < 4; r++) m = fmaxf(m, acc[0][nt][r]);
#pragma unroll
            for (int r = 0; r < 4; r++) m = fmaxf(m, acc[1][nt][r]);
            m = fmaxf(m, __shfl_xor(m, 16));
            m = fmaxf(m, __shfl_xor(m, 32));
            mnt[nt] = m;
        }
        if (lquad == 0) {
#pragma unroll
            for (int nt = 0; nt < 2; nt++) {
                int d = ncol + nt * 16 + lane16;
                outp[((size_t)b * DIM + d) * S + s] = mnt[nt];
            }
        }
    }
}

extern "C" void kernel_launch(void* const* d_in, const int* in_sizes, int n_in,
                              void* d_out, int out_size, void* d_ws, size_t ws_size,
                              hipStream_t stream) {
    const float* xyz = (const float*)d_in[0];
    const float* points = (const float*)d_in[1];
    const float* Wc = (const float*)d_in[2];
    const float* bc = (const float*)d_in[3];
    const float* gamma = (const float*)d_in[4];
    const float* beta = (const float*)d_in[5];
    const float* mean = (const float*)d_in[6];
    const float* var = (const float*)d_in[7];
    const float* Wq = (const float*)d_in[8];
    const float* Wk = (const float*)d_in[9];
    const float* Wv = (const float*)d_in[10];
    const float* Wo = (const float*)d_in[11];
    const float* Wp = (const float*)d_in[12];
    const float* bp = (const float*)d_in[13];

    float* out_xyz = (float*)d_out;
    float* out_pts = out_xyz + B * 3 * S;

    char* ws = (char*)d_ws;
    float* ptsT = (float*)ws;
    size_t off = (size_t)B * N * PTROW * 4;                    // 8,912,896
    float* nxyz = (float*)(ws + off); off += (size_t)B * S * 3 * 4;
    int* gidxp = (int*)(ws + off); off += (size_t)B * S * K * 4;
    float* Wall = (float*)(ws + off); off += 71 * DIM * 4;
    unsigned short* WF = (unsigned short*)(ws + off); off += 77824 * 2;

    k_prep<<<1, 128, 0, stream>>>(Wc, bc, gamma, beta, mean, var, Wp, bp, Wall);
    k_prep2<<<19, 512, 0, stream>>>(Wall, Wq, Wk, Wv, Wo, WF);
    k_transpose<<<(B * N * PTROW + 255) / 256, 256, 0, stream>>>(xyz, points, ptsT);
    k_fps<<<B, 256, 0, stream>>>(xyz, nxyz, out_xyz);
    k_ball<<<B * S / 4, 256, 0, stream>>>(xyz, nxyz, gidxp);
    k_group<<<B * S, 256, 0, stream>>>(ptsT, nxyz, gidxp, WF, Wall + 70 * DIM, out_pts);
}

// Round 4
// 750.814 us; speedup vs baseline: 3.1649x; 1.2229x over previous
//
#include <hip/hip_runtime.h>
#include <math.h>

#define B 8
#define N 4096
#define S 1024
#define K 32
#define CIN 64
#define DIM 128
#define NH 4
#define HD 32
#define PTROW 68   // xyz(3) + points(64) + pad(1)

typedef __attribute__((ext_vector_type(8))) short bfrag;
typedef __attribute__((ext_vector_type(4))) float f32x4;

#define MFMA(a, b, c) __builtin_amdgcn_mfma_f32_16x16x32_bf16((a), (b), (c), 0, 0, 0)

__device__ __forceinline__ unsigned short f2bf(float f) {
    union { float f; unsigned u; } v; v.f = f;
    unsigned r = v.u + 0x7FFFu + ((v.u >> 16) & 1u);
    return (unsigned short)(r >> 16);
}

// ---------------- prep: fold BN + biases + Wp into one [71][128] matrix ----------------
__global__ void k_prep(const float* __restrict__ Wc, const float* __restrict__ bc,
                       const float* __restrict__ gamma, const float* __restrict__ beta,
                       const float* __restrict__ mean, const float* __restrict__ var,
                       const float* __restrict__ Wp, const float* __restrict__ bp,
                       float* __restrict__ Wall) {
    int d = threadIdx.x;
    if (d >= DIM) return;
    float a = gamma[d] / sqrtf(var[d] + 1e-5f);
    for (int c = 0; c < 67; c++) Wall[c * DIM + d] = Wc[d * 67 + c] * a;
    for (int c = 0; c < 3; c++)  Wall[(67 + c) * DIM + d] = Wp[c * DIM + d];
    Wall[70 * DIM + d] = bc[d] * a + beta[d] - mean[d] * a + bp[d];
}

// ---------------- prep2: swizzle weights into MFMA B-fragment order, bf16 ----------------
__global__ void k_prep2(const float* __restrict__ Wall, const float* __restrict__ Wq,
                        const float* __restrict__ Wk, const float* __restrict__ Wv,
                        const float* __restrict__ Wo, unsigned short* __restrict__ WF) {
    int blk = blockIdx.x;  // 0..18
    int mat, kt, base;
    if (blk < 3) { mat = 0; kt = blk; base = 0; }
    else { mat = 1 + (blk - 3) / 4; kt = (blk - 3) % 4; base = 12288 + (mat - 1) * 16384; }
    const float* W = (mat == 0) ? Wall : (mat == 1) ? Wq : (mat == 2) ? Wk : (mat == 3) ? Wv : Wo;
    int tid = threadIdx.x;  // 512
    int gnt = tid >> 6, lane = tid & 63;
    int n = gnt * 16 + (lane & 15);
    int k0 = kt * 32 + (lane >> 4) * 8;
    unsigned short* dst = WF + base + (size_t)((kt * 8 + gnt) * 64 + lane) * 8;
#pragma unroll
    for (int i = 0; i < 8; i++) {
        int k = k0 + i;
        float v = (mat == 0 && k >= 70) ? 0.0f : W[k * 128 + n];
        dst[i] = f2bf(v);
    }
}

// ---------------- transpose points (+xyz) into row-per-point layout ----------------
__global__ void k_transpose(const float* __restrict__ xyz, const float* __restrict__ points,
                            float* __restrict__ ptsT) {
    int idx = blockIdx.x * 256 + threadIdx.x;
    const int total = B * N * PTROW;
    if (idx >= total) return;
    int c = idx % PTROW;
    int n = (idx / PTROW) % N;
    int b = idx / (PTROW * N);
    float v = 0.0f;
    if (c < 3) v = xyz[(b * 3 + c) * N + n];
    else if (c < 67) v = points[(b * CIN + (c - 3)) * N + n];
    ptsT[idx] = v;
}

// ---------------- farthest point sampling (DPP reduce, no in-loop global stores) ----------------
#define FPS_DPP_STEP(CTRL) {                                                                       \
    unsigned h2 = (unsigned)__builtin_amdgcn_update_dpp((int)kh, (int)kh, CTRL, 0xf, 0xf, false);  \
    unsigned l2 = (unsigned)__builtin_amdgcn_update_dpp((int)kl, (int)kl, CTRL, 0xf, 0xf, false);  \
    unsigned long long curk = ((unsigned long long)kh << 32) | kl;                                 \
    unsigned long long nxtk = ((unsigned long long)h2 << 32) | l2;                                 \
    if (nxtk > curk) { kh = h2; kl = l2; }                                                         \
}

__global__ __launch_bounds__(256) void k_fps(const float* __restrict__ xyz,
                                             float* __restrict__ nxyz,
                                             float* __restrict__ out_xyz) {
    const int b = blockIdx.x;
    const float* X = xyz + (size_t)b * 3 * N;
    __shared__ float xs[N], ys[N], zs[N];
    __shared__ float cent[S * 3];
    __shared__ unsigned long long wbuf[2][4];
    const int tid = threadIdx.x;
    const int PT = N / 256;  // 16

    float px[16], py[16], pz[16], pd[16];
#pragma unroll
    for (int i = 0; i < PT; i++) {
        int n = tid + i * 256;
        px[i] = X[n]; py[i] = X[N + n]; pz[i] = X[2 * N + n];
        xs[n] = px[i]; ys[n] = py[i]; zs[n] = pz[i];
        pd[i] = 1e10f;
    }
    __syncthreads();

    float cx = xs[0], cy = ys[0], cz = zs[0];
    for (int t = 0; t < S; t++) {
        if (tid == 0) { cent[t * 3] = cx; cent[t * 3 + 1] = cy; cent[t * 3 + 2] = cz; }
        if (t == S - 1) break;

        float bv = -1.0f; int bi = 0;
#pragma unroll
        for (int i = 0; i < PT; i++) {
            float dx = px[i] - cx, dy = py[i] - cy, dz = pz[i] - cz;
            // match XLA/np: (dx*dx + dy*dy) + dz*dz, no FMA contraction
            float d = __fadd_rn(__fadd_rn(__fmul_rn(dx, dx), __fmul_rn(dy, dy)), __fmul_rn(dz, dz));
            pd[i] = fminf(pd[i], d);
            if (pd[i] > bv) { bv = pd[i]; bi = tid + i * 256; }  // strict >: first idx within thread
        }
        // packed key: max dist, then min index on ties (dist >= 0 -> bits order-preserving)
        unsigned kh = __float_as_uint(bv);
        unsigned kl = 0xFFFFFFFFu - (unsigned)bi;
        // DPP wave-64 max-reduce; lane 63 holds the wave winner
        FPS_DPP_STEP(0x111)  // row_shr:1
        FPS_DPP_STEP(0x112)  // row_shr:2
        FPS_DPP_STEP(0x114)  // row_shr:4
        FPS_DPP_STEP(0x118)  // row_shr:8
        FPS_DPP_STEP(0x142)  // row_bcast:15
        FPS_DPP_STEP(0x143)  // row_bcast:31
        if ((tid & 63) == 63)
            wbuf[t & 1][tid >> 6] = ((unsigned long long)kh << 32) | kl;
        __syncthreads();
        unsigned long long k0 = wbuf[t & 1][0], k1 = wbuf[t & 1][1];
        unsigned long long k2 = wbuf[t & 1][2], k3 = wbuf[t & 1][3];
        unsigned long long kA = k0 > k1 ? k0 : k1;
        unsigned long long kB = k2 > k3 ? k2 : k3;
        unsigned long long km = kA > kB ? kA : kB;
        int best = (int)(0xFFFFFFFFu - (unsigned)km);
        cx = xs[best]; cy = ys[best]; cz = zs[best];
    }
    __syncthreads();
    for (int i = tid; i < S; i += 256) {
        float a = cent[i * 3], c1 = cent[i * 3 + 1], c2 = cent[i * 3 + 2];
        nxyz[(b * S + i) * 3 + 0] = a;
        nxyz[(b * S + i) * 3 + 1] = c1;
        nxyz[(b * S + i) * 3 + 2] = c2;
        out_xyz[b * 3 * S + i] = a;
        out_xyz[b * 3 * S + S + i] = c1;
        out_xyz[b * 3 * S + 2 * S + i] = c2;
    }
}

// ---------------- ball query ----------------
__global__ void k_ball(const float* __restrict__ xyz, const float* __restrict__ nxyz,
                       int* __restrict__ gidx) {
    const int g = blockIdx.x * 4 + (threadIdx.x >> 6);
    const int lane = threadIdx.x & 63;
    const int b = g >> 10;
    const float* X = xyz + (size_t)b * 3 * N;
    float cx = nxyz[g * 3 + 0], cy = nxyz[g * 3 + 1], cz = nxyz[g * 3 + 2];
    int cnt = 0;
    int first = -1;
    for (int base = 0; base < N && cnt < K; base += 64) {
        int n = base + lane;
        float dx = cx - X[n], dy = cy - X[N + n], dz = cz - X[2 * N + n];
        float d = __fadd_rn(__fadd_rn(__fmul_rn(dx, dx), __fmul_rn(dy, dy)), __fmul_rn(dz, dz));
        bool in = (d <= 0.04f);
        unsigned long long m = __ballot(in);
        int pre = __popcll(m & ((1ull << lane) - 1ull));
        if (in && cnt + pre < K) gidx[g * K + cnt + pre] = n;
        if (first < 0 && m) first = base + (int)__ffsll((unsigned long long)m) - 1;
        cnt += __popcll(m);
    }
    if (cnt < K) {
        for (int i = cnt + lane; i < K; i += 64) gidx[g * K + i] = first;
    }
}

// ---------------- fused group kernel, MFMA version ----------------
#define LDS_X   0        // [32][128] bf16 swizzled: x -> P
#define LDS_A   8192     // [32][128] bf16 swizzled: feat -> q -> o
#define LDS_K   16384    // [32][128] bf16 swizzled: k
#define LDS_VT  24576    // v_t [128][56] bf16 (112B rows): v transposed
#define LDS_MISC 38912   // nidx[32] int, ctr[3] float
#define LDS_TOTAL 39056

#define LDSA_READ(off, row, colb) \
    (*(const bfrag*)(smem + (off) + ((row) << 8) + ((colb) ^ (((row) & 7) << 4))))
#define LDS_ST16(off, row, colb, val) \
    (*(unsigned short*)(smem + (off) + ((row) << 8) + ((colb) ^ (((row) & 7) << 4))) = (val))

__global__ __launch_bounds__(256, 4) void k_group(
    const float* __restrict__ ptsT, const float* __restrict__ nxyz,
    const int* __restrict__ gidx, const unsigned short* __restrict__ WF,
    const float* __restrict__ bias, float* __restrict__ outp) {
    __shared__ __align__(16) char smem[LDS_TOTAL];
    const int g = blockIdx.x, b = g >> 10, s = g & 1023;
    const int tid = threadIdx.x;
    const int w = tid >> 6, l = tid & 63;
    const int lane16 = l & 15, lquad = l >> 4;
    const int ncol = w * 32;

    int* nidx = (int*)(smem + LDS_MISC);
    float* ctr = (float*)(smem + LDS_MISC + 128);

    if (tid < K) nidx[tid] = gidx[g * K + tid];
    if (tid >= 64 && tid < 67) ctr[tid - 64] = nxyz[g * 3 + (tid - 64)];
    for (int i = tid; i < 32 * 32; i += 256) {
        int p = i >> 5, c = 64 + (i & 31);
        LDS_ST16(LDS_A, p, c * 2, (unsigned short)0);
    }
    __syncthreads();

    {
        const int p = tid >> 3, j = tid & 7;
        const float* src = ptsT + (size_t)(b * N + nidx[p]) * PTROW;
        float c0 = ctr[0], c1 = ctr[1], c2 = ctr[2];
        for (int c = j; c < 70; c += 8) {
            float v;
            if (c < 3) v = src[c] - (c == 0 ? c0 : c == 1 ? c1 : c2);
            else if (c < 67) v = src[c];
            else v = src[c - 67];
            LDS_ST16(LDS_A, p, c * 2, f2bf(v));
        }
    }
    __syncthreads();

    // ---- GEMM1: x = feat @ Wall + bias ----
    f32x4 accx[2][2];
    {
        float bv0 = bias[ncol + lane16], bv1 = bias[ncol + 16 + lane16];
        accx[0][0] = f32x4{bv0, bv0, bv0, bv0}; accx[1][0] = accx[0][0];
        accx[0][1] = f32x4{bv1, bv1, bv1, bv1}; accx[1][1] = accx[0][1];
        const bfrag* WallF = (const bfrag*)WF;
#pragma unroll
        for (int kt = 0; kt < 3; kt++) {
            bfrag a0 = LDSA_READ(LDS_A, lane16, kt * 64 + lquad * 16);
            bfrag a1 = LDSA_READ(LDS_A, 16 + lane16, kt * 64 + lquad * 16);
            bfrag b0 = WallF[(kt * 8 + w * 2 + 0) * 64 + l];
            bfrag b1 = WallF[(kt * 8 + w * 2 + 1) * 64 + l];
            accx[0][0] = MFMA(a0, b0, accx[0][0]);
            accx[0][1] = MFMA(a0, b1, accx[0][1]);
            accx[1][0] = MFMA(a1, b0, accx[1][0]);
            accx[1][1] = MFMA(a1, b1, accx[1][1]);
        }
#pragma unroll
        for (int mt = 0; mt < 2; mt++)
#pragma unroll
            for (int nt = 0; nt < 2; nt++)
#pragma unroll
                for (int r = 0; r < 4; r++)
                    LDS_ST16(LDS_X, mt * 16 + lquad * 4 + r, (ncol + nt * 16 + lane16) * 2,
                             f2bf(accx[mt][nt][r]));
    }
    __syncthreads();

    // ---- GEMM2-4: q,k,v = x @ {Wq,Wk,Wv} ----
    {
        const bfrag* WQF = (const bfrag*)(WF + 12288);
        const bfrag* WKF = (const bfrag*)(WF + 28672);
        const bfrag* WVF = (const bfrag*)(WF + 45056);
#pragma unroll
        for (int m = 0; m < 3; m++) {
            const bfrag* BW = (m == 0) ? WQF : (m == 1) ? WKF : WVF;
            f32x4 acc[2][2] = {};
#pragma unroll
            for (int kt = 0; kt < 4; kt++) {
                bfrag a0 = LDSA_READ(LDS_X, lane16, kt * 64 + lquad * 16);
                bfrag a1 = LDSA_READ(LDS_X, 16 + lane16, kt * 64 + lquad * 16);
                bfrag b0 = BW[(kt * 8 + w * 2 + 0) * 64 + l];
                bfrag b1 = BW[(kt * 8 + w * 2 + 1) * 64 + l];
                acc[0][0] = MFMA(a0, b0, acc[0][0]);
                acc[0][1] = MFMA(a0, b1, acc[0][1]);
                acc[1][0] = MFMA(a1, b0, acc[1][0]);
                acc[1][1] = MFMA(a1, b1, acc[1][1]);
            }
            if (m < 2) {
                int dst = (m == 0) ? LDS_A : LDS_K;
#pragma unroll
                for (int mt = 0; mt < 2; mt++)
#pragma unroll
                    for (int nt = 0; nt < 2; nt++)
#pragma unroll
                        for (int r = 0; r < 4; r++)
                            LDS_ST16(dst, mt * 16 + lquad * 4 + r, (ncol + nt * 16 + lane16) * 2,
                                     f2bf(acc[mt][nt][r]));
            } else {
#pragma unroll
                for (int mt = 0; mt < 2; mt++)
#pragma unroll
                    for (int nt = 0; nt < 2; nt++)
#pragma unroll
                        for (int r = 0; r < 4; r++) {
                            int d = ncol + nt * 16 + lane16;
                            int j = mt * 16 + lquad * 4 + r;
                            *(unsigned short*)(smem + LDS_VT + d * 112 + j * 2) = f2bf(acc[mt][nt][r]);
                        }
            }
        }
    }
    __syncthreads();

    // ---- scores (head h = w), in-register softmax, P -> LDS_X, PV, o -> LDS_A ----
    {
        const int h = w;
        const int hb = h * 64;
        bfrag aq0 = LDSA_READ(LDS_A, lane16, hb + lquad * 16);
        bfrag aq1 = LDSA_READ(LDS_A, 16 + lane16, hb + lquad * 16);
        bfrag bk0 = LDSA_READ(LDS_K, lane16, hb + lquad * 16);
        bfrag bk1 = LDSA_READ(LDS_K, 16 + lane16, hb + lquad * 16);
        f32x4 sc[2][2] = {};
        sc[0][0] = MFMA(aq0, bk0, sc[0][0]);
        sc[0][1] = MFMA(aq0, bk1, sc[0][1]);
        sc[1][0] = MFMA(aq1, bk0, sc[1][0]);
        sc[1][1] = MFMA(aq1, bk1, sc[1][1]);

        const float scale = 0.17677669529663687f;
        float p_[2][2][4];
        float mx[2][4], sm[2][4];
#pragma unroll
        for (int mt = 0; mt < 2; mt++)
#pragma unroll
            for (int r = 0; r < 4; r++) {
                p_[mt][0][r] = sc[mt][0][r] * scale;
                p_[mt][1][r] = sc[mt][1][r] * scale;
                mx[mt][r] = fmaxf(p_[mt][0][r], p_[mt][1][r]);
            }
#pragma unroll
        for (int d = 1; d < 16; d <<= 1)
#pragma unroll
            for (int mt = 0; mt < 2; mt++)
#pragma unroll
                for (int r = 0; r < 4; r++)
                    mx[mt][r] = fmaxf(mx[mt][r], __shfl_xor(mx[mt][r], d));
#pragma unroll
        for (int mt = 0; mt < 2; mt++)
#pragma unroll
            for (int r = 0; r < 4; r++) {
                float e0 = __expf(p_[mt][0][r] - mx[mt][r]);
                float e1 = __expf(p_[mt][1][r] - mx[mt][r]);
                p_[mt][0][r] = e0; p_[mt][1][r] = e1;
                sm[mt][r] = e0 + e1;
            }
#pragma unroll
        for (int d = 1; d < 16; d <<= 1)
#pragma unroll
            for (int mt = 0; mt < 2; mt++)
#pragma unroll
                for (int r = 0; r < 4; r++)
                    sm[mt][r] += __shfl_xor(sm[mt][r], d);
#pragma unroll
        for (int mt = 0; mt < 2; mt++)
#pragma unroll
            for (int r = 0; r < 4; r++) {
                float inv = 1.0f / sm[mt][r];
                int row = mt * 16 + lquad * 4 + r;
                LDS_ST16(LDS_X, row, (h * 32 + lane16) * 2, f2bf(p_[mt][0][r] * inv));
                LDS_ST16(LDS_X, row, (h * 32 + 16 + lane16) * 2, f2bf(p_[mt][1][r] * inv));
            }

        f32x4 oacc[2][2] = {};
        bfrag ap0 = LDSA_READ(LDS_X, lane16, hb + lquad * 16);
        bfrag ap1 = LDSA_READ(LDS_X, 16 + lane16, hb + lquad * 16);
        bfrag bv0 = *(const bfrag*)(smem + LDS_VT + (h * 32 + lane16) * 112 + lquad * 16);
        bfrag bv1 = *(const bfrag*)(smem + LDS_VT + (h * 32 + 16 + lane16) * 112 + lquad * 16);
        oacc[0][0] = MFMA(ap0, bv0, oacc[0][0]);
        oacc[0][1] = MFMA(ap0, bv1, oacc[0][1]);
        oacc[1][0] = MFMA(ap1, bv0, oacc[1][0]);
        oacc[1][1] = MFMA(ap1, bv1, oacc[1][1]);
#pragma unroll
        for (int mt = 0; mt < 2; mt++)
#pragma unroll
            for (int nt = 0; nt < 2; nt++)
#pragma unroll
                for (int r = 0; r < 4; r++)
                    LDS_ST16(LDS_A, mt * 16 + lquad * 4 + r, (h * 32 + nt * 16 + lane16) * 2,
                             f2bf(oacc[mt][nt][r]));
    }
    __syncthreads();

    // ---- GEMM7: out = x + o @ Wo ; maxpool over 32 points ----
    {
        const bfrag* WOF = (const bfrag*)(WF + 61440);
        f32x4 acc[2][2];
#pragma unroll
        for (int mt = 0; mt < 2; mt++)
#pragma unroll
            for (int nt = 0; nt < 2; nt++) acc[mt][nt] = accx[mt][nt];
#pragma unroll
        for (int kt = 0; kt < 4; kt++) {
            bfrag a0 = LDSA_READ(LDS_A, lane16, kt * 64 + lquad * 16);
            bfrag a1 = LDSA_READ(LDS_A, 16 + lane16, kt * 64 + lquad * 16);
            bfrag b0 = WOF[(kt * 8 + w * 2 + 0) * 64 + l];
            bfrag b1 = WOF[(kt * 8 + w * 2 + 1) * 64 + l];
            acc[0][0] = MFMA(a0, b0, acc[0][0]);
            acc[0][1] = MFMA(a0, b1, acc[0][1]);
            acc[1][0] = MFMA(a1, b0, acc[1][0]);
            acc[1][1] = MFMA(a1, b1, acc[1][1]);
        }
        float mnt[2];
#pragma unroll
        for (int nt = 0; nt < 2; nt++) {
            float m = acc[0][nt][0];
#pragma unroll
            for (int r = 1; r < 4; r++) m = fmaxf(m, acc[0][nt][r]);
#pragma unroll
            for (int r = 0; r < 4; r++) m = fmaxf(m, acc[1][nt][r]);
            m = fmaxf(m, __shfl_xor(m, 16));
            m = fmaxf(m, __shfl_xor(m, 32));
            mnt[nt] = m;
        }
        if (lquad == 0) {
#pragma unroll
            for (int nt = 0; nt < 2; nt++) {
                int d = ncol + nt * 16 + lane16;
                outp[((size_t)b * DIM + d) * S + s] = mnt[nt];
            }
        }
    }
}

extern "C" void kernel_launch(void* const* d_in, const int* in_sizes, int n_in,
                              void* d_out, int out_size, void* d_ws, size_t ws_size,
                              hipStream_t stream) {
    const float* xyz = (const float*)d_in[0];
    const float* points = (const float*)d_in[1];
    const float* Wc = (const float*)d_in[2];
    const float* bc = (const float*)d_in[3];
    const float* gamma = (const float*)d_in[4];
    const float* beta = (const float*)d_in[5];
    const float* mean = (const float*)d_in[6];
    const float* var = (const float*)d_in[7];
    const float* Wq = (const float*)d_in[8];
    const float* Wk = (const float*)d_in[9];
    const float* Wv = (const float*)d_in[10];
    const float* Wo = (const float*)d_in[11];
    const float* Wp = (const float*)d_in[12];
    const float* bp = (const float*)d_in[13];

    float* out_xyz = (float*)d_out;
    float* out_pts = out_xyz + B * 3 * S;

    char* ws = (char*)d_ws;
    float* ptsT = (float*)ws;
    size_t off = (size_t)B * N * PTROW * 4;
    float* nxyz = (float*)(ws + off); off += (size_t)B * S * 3 * 4;
    int* gidxp = (int*)(ws + off); off += (size_t)B * S * K * 4;
    float* Wall = (float*)(ws + off); off += 71 * DIM * 4;
    unsigned short* WF = (unsigned short*)(ws + off); off += 77824 * 2;

    k_prep<<<1, 128, 0, stream>>>(Wc, bc, gamma, beta, mean, var, Wp, bp, Wall);
    k_prep2<<<19, 512, 0, stream>>>(Wall, Wq, Wk, Wv, Wo, WF);
    k_transpose<<<(B * N * PTROW + 255) / 256, 256, 0, stream>>>(xyz, points, ptsT);
    k_fps<<<B, 256, 0, stream>>>(xyz, nxyz, out_xyz);
    k_ball<<<B * S / 4, 256, 0, stream>>>(xyz, nxyz, gidxp);
    k_group<<<B * S, 256, 0, stream>>>(ptsT, nxyz, gidxp, WF, Wall + 70 * DIM, out_pts);
}